// Round 8
// baseline (86.826 us; speedup 1.0000x reference)
//
#include <hip/hip_runtime.h>
#include <math.h>

#define HH 300
#define WW 300
#define CC 4
#define MM 4096
#define KP 640          // padded K (fp8 bytes/row): 2*W=600 -> 640
#define NKC (KP/32)     // 20 k-chunks of 32 B
#define MP 1280         // rows = c*300+h (1200) padded to 1280
#define NP 8192         // 2*M (real | imag output columns)
#define NRB (MP/128)    // 10 row-blocks

typedef __attribute__((ext_vector_type(4))) float f32x4;
typedef __attribute__((ext_vector_type(4))) int int4v;
typedef __attribute__((ext_vector_type(8))) int int8v;

#define TWO_PI 6.283185307179586f

// prep: zero out[0]; build A (MP x KP fp8 e4m3, chunk-major: elem(row,k) at
// ((k/32)*MP+row)*32 + k%32) and B^T (NP x KP fp8, chunk-major).
// Wave layout: 8 rows x 8 j-slots (4 B each) -> every store is a contiguous
// 256-B run across the wave. B: one lane serves rows m AND m+4096 (2x sincos dedup).
__global__ __launch_bounds__(256) void prep_kernel(
    const float* __restrict__ img, const float* __restrict__ csm,
    const float* __restrict__ omega, unsigned char* __restrict__ A,
    unsigned char* __restrict__ B, float* __restrict__ out)
{
    const int bid = blockIdx.x;
    const int t   = threadIdx.x;
    if (bid == 0 && t == 0) out[0] = 0.0f;
    const int lane = t & 63;
    const int jj   = lane & 7;          // 4-B slot within 32-B chunk
    const int rl   = lane >> 3;         // row within the wave's 8-row group

    if (bid < 800) {                    // ---- A: 3200 waves (20 chunks x 160) ----
        int gw = (bid * 256 + t) >> 6;
        int kc = gw / 160;
        int row = (gw - kc * 160) * 8 + rl;
        int k0 = kc * 32 + jj * 4;
        unsigned int word = 0;
        if (row < CC * HH) {
            int c = row / HH;
            int h = row - c * HH;
            float v[4];
            #pragma unroll
            for (int q = 0; q < 4; ++q) {
                int k = k0 + q;
                float vv = 0.0f;
                if (k < 2 * WW) {
                    int w = (k < WW) ? k : k - WW;
                    float im = img[h * WW + w];
                    const float* cs = csm + (((size_t)c * HH + h) * WW + w) * 2;
                    vv = ((k < WW) ? cs[0] : cs[1]) * im;
                }
                v[q] = vv;
            }
            unsigned int lo = (unsigned int)(ushort)__builtin_amdgcn_cvt_pk_fp8_f32(v[0], v[1], 0, false);
            unsigned int hi = (unsigned int)(ushort)__builtin_amdgcn_cvt_pk_fp8_f32(v[2], v[3], 0, false);
            word = lo | (hi << 16);
        }
        *(unsigned int*)(A + ((size_t)kc * MP + row) * 32 + jj * 4) = word;
    } else {                            // ---- B: 10240 waves (20 chunks x 512) ----
        int gw = ((bid - 800) * 256 + t) >> 6;
        int kc = gw / 512;
        int m  = (gw - kc * 512) * 8 + rl;
        int k0 = kc * 32 + jj * 4;
        float om1 = omega[MM + m];
        float p0[4], p1[4];
        #pragma unroll
        for (int q = 0; q < 4; ++q) {
            int k = k0 + q;
            float a0 = 0.0f, a1 = 0.0f;
            if (k < 2 * WW) {
                int w = (k < WW) ? k : k - WW;
                float s, c;
                __sincosf(TWO_PI * om1 * (float)(w - 150), &s, &c);
                // ez_r = c, ez_i = -s. real row: [ez_r | -ez_i]; imag row: [ez_i | ez_r]
                a0 = (k < WW) ? c : s;
                a1 = (k < WW) ? -s : c;
            }
            p0[q] = a0; p1[q] = a1;
        }
        unsigned int lo0 = (unsigned int)(ushort)__builtin_amdgcn_cvt_pk_fp8_f32(p0[0], p0[1], 0, false);
        unsigned int hi0 = (unsigned int)(ushort)__builtin_amdgcn_cvt_pk_fp8_f32(p0[2], p0[3], 0, false);
        unsigned int lo1 = (unsigned int)(ushort)__builtin_amdgcn_cvt_pk_fp8_f32(p1[0], p1[1], 0, false);
        unsigned int hi1 = (unsigned int)(ushort)__builtin_amdgcn_cvt_pk_fp8_f32(p1[2], p1[3], 0, false);
        *(unsigned int*)(B + ((size_t)kc * NP + m) * 32 + jj * 4)      = lo0 | (hi0 << 16);
        *(unsigned int*)(B + ((size_t)kc * NP + m + MM) * 32 + jj * 4) = lo1 | (hi1 << 16);
    }
}

// Barrier-free fp8 MX GEMM, 128-row x 64-col tiles (grid 128x10 = 1280 blocks,
// 5.0 blocks/CU). Mixed-coil epilogue: 2 coil slots per tile, P2[rb][slot][n].
__global__ __launch_bounds__(256) void gemm_kernel(
    const unsigned char* __restrict__ A, const unsigned char* __restrict__ B,
    const float* __restrict__ omega, float2* __restrict__ P2)
{
    __shared__ float2 red[2][64];

    const int t    = threadIdx.x;
    const int wave = t >> 6;
    const int ln   = t & 63;
    const int row0 = blockIdx.y * 128;
    const int col0 = blockIdx.x * 64;
    const int wr = wave >> 1;           // 0..1: 64-row half
    const int wc = wave & 1;            // 0..1: 32-col half
    const int lr = ln & 15;
    const int lq = ln >> 4;

    if (t < 64) { red[0][t] = make_float2(0.f, 0.f); red[1][t] = make_float2(0.f, 0.f); }

    const int arow = row0 + wr * 64 + lr;
    const int bcol = col0 + wc * 32 + lr;

    f32x4 acc[4][2] = {};

    #pragma unroll
    for (int kc = 0; kc < NKC; kc += 4) {   // 5 K-steps of 128, fully unrolled
        int8v a[4], b[2];
        #pragma unroll
        for (int i = 0; i < 4; ++i) {
            const unsigned char* pA = A + ((size_t)(kc + lq) * MP + arow + i * 16) * 32;
            int4v lo = *(const int4v*)pA;
            int4v hi = *(const int4v*)(pA + 16);
            a[i] = __builtin_shufflevector(lo, hi, 0, 1, 2, 3, 4, 5, 6, 7);
        }
        #pragma unroll
        for (int j = 0; j < 2; ++j) {
            const unsigned char* pB = B + ((size_t)(kc + lq) * NP + bcol + j * 16) * 32;
            int4v lo = *(const int4v*)pB;
            int4v hi = *(const int4v*)(pB + 16);
            b[j] = __builtin_shufflevector(lo, hi, 0, 1, 2, 3, 4, 5, 6, 7);
        }
        #pragma unroll
        for (int i = 0; i < 4; ++i)
            #pragma unroll
            for (int j = 0; j < 2; ++j)
                acc[i][j] = __builtin_amdgcn_mfma_scale_f32_16x16x128_f8f6f4(
                    a[i], b[j], acc[i][j], 0, 0,
                    0, 0x7f7f7f7f, 0, 0x7f7f7f7f);    // unit E8M0 scales
    }

    __syncthreads();   // red[] init visible before epilogue atomics

    // ---- fused stage-2 epilogue: per coil slot, Sum_h acc * ey(m,h) ----
    const int cmin   = row0 / HH;               // tile's low coil
    const int cbound = (cmin + 1) * HH;         // first row of next coil

    #pragma unroll
    for (int j = 0; j < 2; ++j) {
        const int jcol = wc * 32 + j * 16 + lr;        // 0..63
        const int m = (col0 + jcol) & (MM - 1);
        const float om0 = omega[m];
        float ss, sc;
        __sincosf(TWO_PI * om0, &ss, &sc);
        const float str = sc, sti = -ss;               // step = exp(-2pi i om0)

        float p0r = 0.f, p0i = 0.f, p1r = 0.f, p1i = 0.f;
        #pragma unroll
        for (int i = 0; i < 4; ++i) {
            const int g  = row0 + wr * 64 + i * 16 + lq * 4;   // quad base row
            const bool hi = (g >= cbound);                     // quad is coil-uniform
            const int h  = g - (hi ? cbound : cmin * HH);
            float sn, cs;
            __sincosf(TWO_PI * om0 * (float)(h - 150), &sn, &cs);
            float er = cs, ei = -sn;                           // ey at this h
            float qr = 0.f, qi = 0.f;
            #pragma unroll
            for (int r = 0; r < 4; ++r) {
                const float v = acc[i][j][r];
                qr = fmaf(v, er, qr);
                qi = fmaf(v, ei, qi);
                float nr = er * str - ei * sti;
                ei = er * sti + ei * str;
                er = nr;
            }
            p0r += hi ? 0.f : qr;  p0i += hi ? 0.f : qi;
            p1r += hi ? qr : 0.f;  p1i += hi ? qi : 0.f;
        }
        p0r += __shfl_down(p0r, 32); p0i += __shfl_down(p0i, 32);
        p1r += __shfl_down(p1r, 32); p1i += __shfl_down(p1i, 32);
        p0r += __shfl_down(p0r, 16); p0i += __shfl_down(p0i, 16);
        p1r += __shfl_down(p1r, 16); p1i += __shfl_down(p1i, 16);
        if (lq == 0) {
            atomicAdd(&red[0][jcol].x, p0r);
            atomicAdd(&red[0][jcol].y, p0i);
            atomicAdd(&red[1][jcol].x, p1r);
            atomicAdd(&red[1][jcol].y, p1i);
        }
    }
    __syncthreads();

    if (t < 64) {
        const int rb = blockIdx.y;
        P2[(size_t)(rb * 2 + 0) * NP + col0 + t] = red[0][t];
        P2[(size_t)(rb * 2 + 1) * NP + col0 + t] = red[1][t];
    }
}

// loss: k[c,m] assembled from (rowblock, slot) partials via a constant table.
__global__ __launch_bounds__(64) void loss_kernel(
    const float2* __restrict__ P2, const float* __restrict__ kdata,
    const float* __restrict__ omega, float* __restrict__ out)
{
    // coil c <- list of (rb*2+slot) entries covering rows [300c, 300c+300)
    const int cnt[4] = {3, 3, 4, 3};
    const int off[4] = {0, 3, 6, 10};
    const int ent[13] = {0, 2, 4,  5, 6, 8,  9, 10, 12, 14,  15, 16, 18};

    const int t = blockIdx.x * 64 + threadIdx.x;   // 0..16383
    const int c = t >> 12;                         // wave-uniform
    const int m = t & (MM - 1);

    float2 krc = make_float2(0.f, 0.f);            // Sum Cr*ey (complex)
    float2 kic = make_float2(0.f, 0.f);            // Sum Ci*ey (complex)
    const int e0 = off[c], n = cnt[c];
    for (int e = e0; e < e0 + n; ++e) {
        const size_t base = (size_t)ent[e] * NP;
        float2 p0 = P2[base + m];
        float2 p1 = P2[base + m + MM];
        krc.x += p0.x; krc.y += p0.y;
        kic.x += p1.x; kic.y += p1.y;
    }
    float kr = (krc.x - kic.y) * (1.0f / 300.0f);
    float ki = (krc.y + kic.x) * (1.0f / 300.0f);

    const float om0 = omega[m];
    const float om1 = omega[MM + m];
    const size_t kidx = ((size_t)c * MM + m) * 2;
    const float kdr = kdata[kidx];
    const float kdi = kdata[kidx + 1];
    const float w0 = om0 * TWO_PI, w1 = om1 * TWO_PI;
    const float wg = sqrtf(w0 * w0 + w1 * w1) + 1.0f;
    const float dr = wg * (kr - kdr);
    const float di = wg * (ki - kdi);
    float val = (dr * dr + di * di) * (1.0f / (2.0f * CC * MM));

    #pragma unroll
    for (int o = 32; o > 0; o >>= 1) val += __shfl_down(val, o);
    if (threadIdx.x == 0) atomicAdd(out, val);
}

extern "C" void kernel_launch(void* const* d_in, const int* in_sizes, int n_in,
                              void* d_out, int out_size, void* d_ws, size_t ws_size,
                              hipStream_t stream) {
    const float* img   = (const float*)d_in[0];   // (300,300,1)
    const float* kdata = (const float*)d_in[1];   // (1,4,4096,2)
    const float* omega = (const float*)d_in[2];   // (1,2,4096)
    const float* csm   = (const float*)d_in[4];   // (4,300,300,2)
    float* out = (float*)d_out;

    unsigned char* Aws = (unsigned char*)d_ws;                  // MP*KP  = 0.82 MB
    unsigned char* Bws = (unsigned char*)d_ws + (1u << 20);     // NP*KP  = 5.24 MB
    float2*        P2  = (float2*)((char*)d_ws + (8u << 20));   // 20*NP*8 = 1.31 MB

    prep_kernel<<<800 + 2560, 256, 0, stream>>>(img, csm, omega, Aws, Bws, out);
    gemm_kernel<<<dim3(NP / 64, MP / 128), 256, 0, stream>>>(Aws, Bws, omega, P2);
    loss_kernel<<<CC * MM / 64, 64, 0, stream>>>(P2, kdata, omega, out);
}

// Round 9
// 86.300 us; speedup vs baseline: 1.0061x; 1.0061x over previous
//
#include <hip/hip_runtime.h>
#include <math.h>

#define HH 300
#define WW 300
#define CC 4
#define MM 4096
#define KP 640          // padded K (fp8 bytes/row), 2*W=600 -> 640
#define NKC (KP/32)     // 20 k-chunks of 32 B
#define CSTRIDE 384     // per-coil row stride (3*128: every 128-row tile coil-pure)
#define MP (CC*CSTRIDE) // 1536
#define NP 8192         // 2*M (real | imag output columns)
#define NRB (MP/128)    // 12 row-blocks

typedef __attribute__((ext_vector_type(4))) float f32x4;
typedef __attribute__((ext_vector_type(4))) int int4v;
typedef __attribute__((ext_vector_type(8))) int int8v;

#define TWO_PI 6.283185307179586f

// Chunk-major: elem (row, k) of an R-row matrix at ((k/32)*R + row)*32 + (k%32).

// prep: zero out[0]; build A (MP x KP fp8 e4m3, chunk-major) and B^T (NP x KP,
// chunk-major), fully-coalesced stores: wave = 8 rows x 8 4-B slots -> every
// store instruction is a contiguous 256-B run. Values identical to round 7.
__global__ __launch_bounds__(256) void prep_kernel(
    const float* __restrict__ img, const float* __restrict__ csm,
    const float* __restrict__ omega, unsigned char* __restrict__ A,
    unsigned char* __restrict__ B, float* __restrict__ out)
{
    const int bid = blockIdx.x;
    const int t   = threadIdx.x;
    if (bid == 0 && t == 0) out[0] = 0.0f;
    const int lane = t & 63;
    const int jj   = lane & 7;          // 4-B slot within 32-B chunk
    const int rl   = lane >> 3;         // row within the wave's 8-row group

    if (bid < 960) {                    // ---- A: 3840 waves (20 chunks x 192) ----
        int gw = (bid * 256 + t) >> 6;
        int kc = gw / 192;
        int row = (gw - kc * 192) * 8 + rl;       // 0..1535
        int k0 = kc * 32 + jj * 4;
        unsigned int word = 0;
        int c = row / CSTRIDE;
        int h = row - c * CSTRIDE;
        if (h < HH) {
            float v[4];
            #pragma unroll
            for (int q = 0; q < 4; ++q) {
                int k = k0 + q;
                float vv = 0.0f;
                if (k < 2 * WW) {
                    int w = (k < WW) ? k : k - WW;
                    float im = img[h * WW + w];
                    const float* cs = csm + (((size_t)c * HH + h) * WW + w) * 2;
                    vv = ((k < WW) ? cs[0] : cs[1]) * im;
                }
                v[q] = vv;
            }
            unsigned int lo = (unsigned int)(ushort)__builtin_amdgcn_cvt_pk_fp8_f32(v[0], v[1], 0, false);
            unsigned int hi = (unsigned int)(ushort)__builtin_amdgcn_cvt_pk_fp8_f32(v[2], v[3], 0, false);
            word = lo | (hi << 16);
        }
        *(unsigned int*)(A + ((size_t)kc * MP + row) * 32 + jj * 4) = word;
    } else {                            // ---- B: 10240 waves (20 chunks x 512) ----
        int gw = ((bid - 960) * 256 + t) >> 6;
        int kc = gw / 512;
        int m  = (gw - kc * 512) * 8 + rl;
        int k0 = kc * 32 + jj * 4;
        float om1 = omega[MM + m];
        float p0[4], p1[4];
        #pragma unroll
        for (int q = 0; q < 4; ++q) {
            int k = k0 + q;
            float a0 = 0.0f, a1 = 0.0f;
            if (k < 2 * WW) {
                int w = (k < WW) ? k : k - WW;
                float s, c;
                __sincosf(TWO_PI * om1 * (float)(w - 150), &s, &c);
                // ez_r = c, ez_i = -s. real row: [ez_r | -ez_i]; imag row: [ez_i | ez_r]
                a0 = (k < WW) ? c : s;
                a1 = (k < WW) ? -s : c;
            }
            p0[q] = a0; p1[q] = a1;
        }
        unsigned int lo0 = (unsigned int)(ushort)__builtin_amdgcn_cvt_pk_fp8_f32(p0[0], p0[1], 0, false);
        unsigned int hi0 = (unsigned int)(ushort)__builtin_amdgcn_cvt_pk_fp8_f32(p0[2], p0[3], 0, false);
        unsigned int lo1 = (unsigned int)(ushort)__builtin_amdgcn_cvt_pk_fp8_f32(p1[0], p1[1], 0, false);
        unsigned int hi1 = (unsigned int)(ushort)__builtin_amdgcn_cvt_pk_fp8_f32(p1[2], p1[3], 0, false);
        *(unsigned int*)(B + ((size_t)kc * NP + m) * 32 + jj * 4)      = lo0 | (hi0 << 16);
        *(unsigned int*)(B + ((size_t)kc * NP + m + MM) * 32 + jj * 4) = lo1 | (hi1 << 16);
    }
}

// Barrier-free fp8 MX GEMM (round-7 structure, verbatim) + __launch_bounds__
// min-waves=3 to pin VGPRs <= ~170 so 3 waves/SIMD stay resident.
__global__ __launch_bounds__(256, 3) void gemm_kernel(
    const unsigned char* __restrict__ A, const unsigned char* __restrict__ B,
    const float* __restrict__ omega, float2* __restrict__ P)
{
    __shared__ float2 red[128];

    const int t    = threadIdx.x;
    const int wave = t >> 6;
    const int ln   = t & 63;
    const int row0 = blockIdx.y * 128;
    const int col0 = blockIdx.x * 128;
    const int wr = wave >> 1, wc = wave & 1;
    const int lr = ln & 15;
    const int lq = ln >> 4;

    if (t < 128) red[t] = make_float2(0.0f, 0.0f);

    const int arow = row0 + wr * 64 + lr;   // base row for this lane's A frags
    const int bcol = col0 + wc * 64 + lr;   // base col for this lane's B frags

    f32x4 acc[4][4] = {};

    #pragma unroll
    for (int kc = 0; kc < NKC; kc += 4) {   // 5 fully-unrolled K-steps (K=128 each)
        int8v a[4], b[4];
        #pragma unroll
        for (int i = 0; i < 4; ++i) {
            const unsigned char* pA = A + ((size_t)(kc + lq) * MP + arow + i * 16) * 32;
            int4v lo = *(const int4v*)pA;
            int4v hi = *(const int4v*)(pA + 16);
            a[i] = __builtin_shufflevector(lo, hi, 0, 1, 2, 3, 4, 5, 6, 7);
        }
        #pragma unroll
        for (int j = 0; j < 4; ++j) {
            const unsigned char* pB = B + ((size_t)(kc + lq) * NP + bcol + j * 16) * 32;
            int4v lo = *(const int4v*)pB;
            int4v hi = *(const int4v*)(pB + 16);
            b[j] = __builtin_shufflevector(lo, hi, 0, 1, 2, 3, 4, 5, 6, 7);
        }
        #pragma unroll
        for (int i = 0; i < 4; ++i)
            #pragma unroll
            for (int j = 0; j < 4; ++j)
                acc[i][j] = __builtin_amdgcn_mfma_scale_f32_16x16x128_f8f6f4(
                    a[i], b[j], acc[i][j], 0, 0,      // cbsz=0 (fp8), blgp=0 (fp8)
                    0, 0x7f7f7f7f, 0, 0x7f7f7f7f);    // unit E8M0 scales
    }

    __syncthreads();   // red[] init visible before epilogue atomics

    // ---- fused stage-2 epilogue: P[rb][col] = sum_h acc * ey(m,h) ----
    const int c  = row0 / CSTRIDE;   // block-uniform (CSTRIDE = 3*128)
    const int h0 = row0 - c * CSTRIDE;

    #pragma unroll
    for (int j = 0; j < 4; ++j) {
        const int jcol = wc * 64 + j * 16 + lr;
        const int m = (col0 + jcol) & (MM - 1);
        const float om0 = omega[m];
        float ss, sc;
        __sincosf(TWO_PI * om0, &ss, &sc);
        const float str = sc, sti = -ss;               // step = exp(-2pi i om0)
        float s2r = str * str - sti * sti, s2i = 2.0f * str * sti;
        float s4r = s2r * s2r - s2i * s2i, s4i = 2.0f * s2r * s2i;
        float s8r = s4r * s4r - s4i * s4i, s8i = 2.0f * s4r * s4i;
        float s16r = s8r * s8r - s8i * s8i, s16i = 2.0f * s8r * s8i;

        const int hb0 = h0 + wr * 64 + lq * 4;
        float sn, cs;
        __sincosf(TWO_PI * om0 * (float)(hb0 - 150), &sn, &cs);
        float byr = cs, byi = -sn;                     // ey at h = hb0

        float pr = 0.0f, pi = 0.0f;
        #pragma unroll
        for (int i = 0; i < 4; ++i) {
            float er = byr, ei = byi;
            #pragma unroll
            for (int r = 0; r < 4; ++r) {
                const float v = acc[i][j][r];
                pr = fmaf(v, er, pr);
                pi = fmaf(v, ei, pi);
                float nr = er * str - ei * sti;
                ei = er * sti + ei * str;
                er = nr;
            }
            float nbr = byr * s16r - byi * s16i;       // advance base by 16 rows
            byi = byr * s16i + byi * s16r;
            byr = nbr;
        }
        pr += __shfl_down(pr, 32); pi += __shfl_down(pi, 32);
        pr += __shfl_down(pr, 16); pi += __shfl_down(pi, 16);
        if (lq == 0) {
            atomicAdd(&red[jcol].x, pr);
            atomicAdd(&red[jcol].y, pi);
        }
    }
    __syncthreads();

    if (t < 128) {
        const int rb = row0 >> 7;
        P[(size_t)rb * NP + col0 + t] = red[t];
    }
}

// loss: k[c,m] from 3 row-block partials. 256 blocks x 64 threads (one wave each).
__global__ __launch_bounds__(64) void loss_kernel(
    const float2* __restrict__ P, const float* __restrict__ kdata,
    const float* __restrict__ omega, float* __restrict__ out)
{
    const int t = blockIdx.x * 64 + threadIdx.x;   // 0..16383
    const int c = t >> 12;
    const int m = t & (MM - 1);

    float kr = 0.0f, ki = 0.0f;
    #pragma unroll
    for (int q = 0; q < 3; ++q) {
        const int rb = 3 * c + q;
        float2 p0 = P[(size_t)rb * NP + m];          // real-col partial
        float2 p1 = P[(size_t)rb * NP + m + MM];     // imag-col partial
        kr += p0.x - p1.y;
        ki += p0.y + p1.x;
    }
    kr *= (1.0f / 300.0f);
    ki *= (1.0f / 300.0f);

    const float om0 = omega[m];
    const float om1 = omega[MM + m];
    const size_t kidx = ((size_t)c * MM + m) * 2;
    const float kdr = kdata[kidx];
    const float kdi = kdata[kidx + 1];
    const float w0 = om0 * TWO_PI, w1 = om1 * TWO_PI;
    const float wg = sqrtf(w0 * w0 + w1 * w1) + 1.0f;
    const float dr = wg * (kr - kdr);
    const float di = wg * (ki - kdi);
    float val = (dr * dr + di * di) * (1.0f / (2.0f * CC * MM));

    #pragma unroll
    for (int off = 32; off > 0; off >>= 1) val += __shfl_down(val, off);
    if (threadIdx.x == 0) atomicAdd(out, val);
}

extern "C" void kernel_launch(void* const* d_in, const int* in_sizes, int n_in,
                              void* d_out, int out_size, void* d_ws, size_t ws_size,
                              hipStream_t stream) {
    const float* img   = (const float*)d_in[0];   // (300,300,1)
    const float* kdata = (const float*)d_in[1];   // (1,4,4096,2)
    const float* omega = (const float*)d_in[2];   // (1,2,4096)
    const float* csm   = (const float*)d_in[4];   // (4,300,300,2)
    float* out = (float*)d_out;

    unsigned char* Aws = (unsigned char*)d_ws;                  // MP*KP  = 0.98 MB
    unsigned char* Bws = (unsigned char*)d_ws + (1u << 20);     // NP*KP  = 5.24 MB
    float2*        Pws = (float2*)((char*)d_ws + (8u << 20));   // NRB*NP*8 = 786 KB

    prep_kernel<<<960 + 2560, 256, 0, stream>>>(img, csm, omega, Aws, Bws, out);
    gemm_kernel<<<dim3(NP / 128, MP / 128), 256, 0, stream>>>(Aws, Bws, omega, Pws);
    loss_kernel<<<CC * MM / 64, 64, 0, stream>>>(Pws, kdata, omega, out);
}